// Round 3
// baseline (1015.539 us; speedup 1.0000x reference)
//
#include <hip/hip_runtime.h>
#include <math.h>

// Wave-uniform broadcast of lane k's value (VALU v_readlane, avoids LDS pipe)
__device__ __forceinline__ float bcast(float v, int k) {
  return __int_as_float(__builtin_amdgcn_readlane(__float_as_int(v), k));
}

// ---------------- CSR build: histogram ----------------
__global__ __launch_bounds__(256) void hist_k(const int* __restrict__ dst, int* __restrict__ deg, int E) {
  for (int e = blockIdx.x * blockDim.x + threadIdx.x; e < E; e += gridDim.x * blockDim.x)
    atomicAdd(&deg[dst[e]], 1);
}

// ---------------- CSR build: 3-kernel exclusive scan ----------------
__global__ __launch_bounds__(1024) void scan1_k(const int* __restrict__ deg, int* __restrict__ rp,
                                                int* __restrict__ bsum, int n) {
  __shared__ int buf[2][1024];
  int tid = threadIdx.x;
  int i = blockIdx.x * 1024 + tid;
  int v = (i < n) ? deg[i] : 0;
  int pp = 0;
  buf[0][tid] = v;
  __syncthreads();
  for (int off = 1; off < 1024; off <<= 1) {
    int t = buf[pp][tid];
    if (tid >= off) t += buf[pp][tid - off];
    buf[pp ^ 1][tid] = t;
    pp ^= 1;
    __syncthreads();
  }
  int inc = buf[pp][tid];
  if (i < n) rp[i] = inc - v;               // exclusive within block
  if (tid == 1023) bsum[blockIdx.x] = inc;  // block total
}

__global__ __launch_bounds__(256) void scan2_k(int* __restrict__ bsum, int nb) {
  __shared__ int buf[2][256];
  int tid = threadIdx.x;
  int v = (tid < nb) ? bsum[tid] : 0;
  int pp = 0;
  buf[0][tid] = v;
  __syncthreads();
  for (int off = 1; off < 256; off <<= 1) {
    int t = buf[pp][tid];
    if (tid >= off) t += buf[pp][tid - off];
    buf[pp ^ 1][tid] = t;
    pp ^= 1;
    __syncthreads();
  }
  if (tid < nb) bsum[tid] = buf[pp][tid] - v;  // exclusive block offsets
}

__global__ __launch_bounds__(1024) void scan3_k(int* __restrict__ rp, int* __restrict__ cur,
                                                const int* __restrict__ bsum, int n, int E) {
  int i = blockIdx.x * 1024 + threadIdx.x;
  if (i < n) {
    int v = rp[i] + bsum[blockIdx.x];
    rp[i] = v;
    cur[i] = v;
  }
  if (i == 0) rp[n] = E;
}

// ---------------- CSR build: counting-sort scatter (packs src+weight) ----------------
__global__ __launch_bounds__(256) void scatter_k(const int* __restrict__ src, const int* __restrict__ dst,
                                                 const float* __restrict__ w, int* __restrict__ cur,
                                                 int2* __restrict__ edge, int E) {
  for (int e = blockIdx.x * blockDim.x + threadIdx.x; e < E; e += gridDim.x * blockDim.x) {
    int d = dst[e];
    int pos = atomicAdd(&cur[d], 1);
    edge[pos] = make_int2(src[e], __float_as_int(w[e]));
  }
}

// ---------------- h = relu(x @ W_in + b_in), 1-deep input prefetch ----------------
__global__ __launch_bounds__(256) void ingemm_k(const float* __restrict__ x, const float* __restrict__ Win,
                                                const float* __restrict__ bin, float* __restrict__ x0, int n) {
  int lane = threadIdx.x & 63;
  int wave = threadIdx.x >> 6;
  int S = gridDim.x * 4;
  float Wreg[128];
#pragma unroll
  for (int k = 0; k < 128; ++k) Wreg[k] = Win[k * 64 + lane];
  float bb = bin[lane];
  int node = blockIdx.x * 4 + wave;
  if (node >= n) return;
  float xa = x[(size_t)node * 128 + lane];
  float xb = x[(size_t)node * 128 + 64 + lane];
  for (; node < n; node += S) {
    int nn = node + S;
    float nxa = 0.f, nxb = 0.f;
    if (nn < n) {
      nxa = x[(size_t)nn * 128 + lane];
      nxb = x[(size_t)nn * 128 + 64 + lane];
    }
    float a0 = 0.f, a1 = 0.f;
#pragma unroll
    for (int k = 0; k < 64; k += 2) {
      a0 = fmaf(bcast(xa, k), Wreg[k], a0);
      a1 = fmaf(bcast(xa, k + 1), Wreg[k + 1], a1);
    }
#pragma unroll
    for (int k = 0; k < 64; k += 2) {
      a0 = fmaf(bcast(xb, k), Wreg[64 + k], a0);
      a1 = fmaf(bcast(xb, k + 1), Wreg[64 + k + 1], a1);
    }
    float r = a0 + a1 + bb;
    x0[(size_t)node * 64 + lane] = fmaxf(r, 0.f);
    xa = nxa;
    xb = nxb;
  }
}

// ---------------- one GCNII layer: 3-stage software-pipelined ----------------
// Per wave, three node-contexts in flight:
//   A: 16 gathers (4 float4/lane) issued one body earlier -> compute now
//   B: edges arrived -> issue gathers
//   C: rp arrived -> load 16 edges + prefetch x0
//   D: issue rp loads (becomes new C)
struct St {
  int beg, end;
  int2 e0, e1, e2, e3;      // 16 edges: slot t covers edge beg+t*4+q
  float4 v0, v1, v2, v3;    // gathered rows (quad fq)
  float x0v;
};

__global__ __launch_bounds__(256) void layer_k(const float4* __restrict__ hin4, const float* __restrict__ x0,
                                               const int* __restrict__ rp, const int2* __restrict__ edge,
                                               const float* __restrict__ W, float* __restrict__ hout,
                                               float beta, int n) {
  int lane = threadIdx.x & 63;
  int wave = threadIdx.x >> 6;
  int q = lane >> 4;    // edge slot 0..3
  int fq = lane & 15;   // feature quad 0..15
  float Wreg[64];
#pragma unroll
  for (int k = 0; k < 64; ++k) Wreg[k] = W[k * 64 + lane];

  const int S = gridDim.x * 4;
  const int node0 = blockIdx.x * 4 + wave;
  if (node0 >= n) return;
  const int total = (n - 1 - node0) / S + 1;  // valid nodes for this wave

  auto loadRP = [&](int node, St& s) {
    if (node < n) {
      s.beg = rp[node];
      s.end = rp[node + 1];
      s.x0v = x0[(size_t)node * 64 + lane];
    } else {
      s.beg = 0; s.end = 0; s.x0v = 0.f;
    }
  };
  auto loadEdges = [&](St& s) {
    int b = s.beg, e = s.end;
    int i0 = b + q, i1 = b + 4 + q, i2 = b + 8 + q, i3 = b + 12 + q;
    s.e0 = (i0 < e) ? edge[i0] : make_int2(0, 0);
    s.e1 = (i1 < e) ? edge[i1] : make_int2(0, 0);
    s.e2 = (i2 < e) ? edge[i2] : make_int2(0, 0);
    s.e3 = (i3 < e) ? edge[i3] : make_int2(0, 0);
  };
  auto issueGathers = [&](St& s) {
    s.v0 = hin4[(size_t)s.e0.x * 16 + fq];
    s.v1 = hin4[(size_t)s.e1.x * 16 + fq];
    s.v2 = hin4[(size_t)s.e2.x * 16 + fq];
    s.v3 = hin4[(size_t)s.e3.x * 16 + fq];
  };
  auto computeStore = [&](St& s, int node) {
    float4 acc;
    float w0 = __int_as_float(s.e0.y), w1 = __int_as_float(s.e1.y);
    float w2 = __int_as_float(s.e2.y), w3 = __int_as_float(s.e3.y);
    acc.x = s.v0.x * w0; acc.y = s.v0.y * w0; acc.z = s.v0.z * w0; acc.w = s.v0.w * w0;
    acc.x = fmaf(s.v1.x, w1, acc.x); acc.y = fmaf(s.v1.y, w1, acc.y);
    acc.z = fmaf(s.v1.z, w1, acc.z); acc.w = fmaf(s.v1.w, w1, acc.w);
    acc.x = fmaf(s.v2.x, w2, acc.x); acc.y = fmaf(s.v2.y, w2, acc.y);
    acc.z = fmaf(s.v2.z, w2, acc.z); acc.w = fmaf(s.v2.w, w2, acc.w);
    acc.x = fmaf(s.v3.x, w3, acc.x); acc.y = fmaf(s.v3.y, w3, acc.y);
    acc.z = fmaf(s.v3.z, w3, acc.z); acc.w = fmaf(s.v3.w, w3, acc.w);
    // rare fallback: degree > 16
    if (s.beg + 16 < s.end) {
      for (int e0i = s.beg + 16; e0i < s.end; e0i += 4) {
        int i = e0i + q;
        int2 ed = (i < s.end) ? edge[i] : make_int2(0, 0);
        float4 v = hin4[(size_t)ed.x * 16 + fq];
        float w = __int_as_float(ed.y);
        acc.x = fmaf(v.x, w, acc.x); acc.y = fmaf(v.y, w, acc.y);
        acc.z = fmaf(v.z, w, acc.z); acc.w = fmaf(v.w, w, acc.w);
      }
    }
    // sum 4 edge slots
#pragma unroll
    for (int m = 16; m <= 32; m <<= 1) {
      acc.x += __shfl_xor(acc.x, m, 64);
      acc.y += __shfl_xor(acc.y, m, 64);
      acc.z += __shfl_xor(acc.z, m, 64);
      acc.w += __shfl_xor(acc.w, m, 64);
    }
    // redistribute to lane = feature
    int srcl = lane >> 2;
    float r0 = __shfl(acc.x, srcl, 64);
    float r1 = __shfl(acc.y, srcl, 64);
    float r2 = __shfl(acc.z, srcl, 64);
    float r3 = __shfl(acc.w, srcl, 64);
    int j = lane & 3;
    float aggv = (j == 0) ? r0 : (j == 1) ? r1 : (j == 2) ? r2 : r3;
    float hh = fmaf(0.9f, aggv, 0.1f * s.x0v);
    float d0 = 0.f, d1 = 0.f;
#pragma unroll
    for (int k = 0; k < 64; k += 2) {
      d0 = fmaf(bcast(hh, k), Wreg[k], d0);
      d1 = fmaf(bcast(hh, k + 1), Wreg[k + 1], d1);
    }
    float o = (1.f - beta) * hh + beta * (d0 + d1);
    if (node < n) hout[(size_t)node * 64 + lane] = fmaxf(o, 0.f);
  };
  auto body = [&](St& A, St& B, St& C, int nodeA, int nodeD) {
    issueGathers(B);          // B.ed arrived (loaded one body ago)
    loadEdges(C);             // C.rp arrived (loaded one body ago)
    int nb = 0, ne = 0; float nx = 0.f;
    if (nodeD < n) { nb = rp[nodeD]; ne = rp[nodeD + 1]; nx = x0[(size_t)nodeD * 64 + lane]; }
    computeStore(A, nodeA);   // A.v arrived (issued one body ago)
    A.beg = nb; A.end = ne; A.x0v = nx;   // A becomes new rp-stage
  };

  St A, B, C;
  // prologue (stalls once)
  loadRP(node0, A); loadEdges(A); issueGathers(A);
  loadRP(node0 + S, B); loadEdges(B);
  loadRP(node0 + 2 * S, C);

  for (int j = 0; j < total; j += 3) {
    int base = node0 + j * S;
    body(A, B, C, base,         base + 3 * S);
    body(B, C, A, base + S,     base + 4 * S);
    body(C, A, B, base + 2 * S, base + 5 * S);
  }
}

// ---------------- out = log_softmax(h @ W_out + b_out), 1-deep prefetch ----------------
__global__ __launch_bounds__(256) void out_k(const float* __restrict__ h, const float* __restrict__ Wout,
                                             const float* __restrict__ bout, float* __restrict__ out, int n) {
  int lane = threadIdx.x & 63;
  int wave = threadIdx.x >> 6;
  int S = gridDim.x * 4;
  float Wreg[64];
#pragma unroll
  for (int k = 0; k < 64; ++k) Wreg[k] = (lane < 40) ? Wout[k * 40 + lane] : 0.f;
  float bb = (lane < 40) ? bout[lane] : 0.f;
  int node = blockIdx.x * 4 + wave;
  if (node >= n) return;
  float hv = h[(size_t)node * 64 + lane];
  for (; node < n; node += S) {
    int nn = node + S;
    float nhv = (nn < n) ? h[(size_t)nn * 64 + lane] : 0.f;
    float d0 = 0.f, d1 = 0.f;
#pragma unroll
    for (int k = 0; k < 64; k += 2) {
      d0 = fmaf(bcast(hv, k), Wreg[k], d0);
      d1 = fmaf(bcast(hv, k + 1), Wreg[k + 1], d1);
    }
    float val = (lane < 40) ? (d0 + d1 + bb) : -INFINITY;
    float m = val;
#pragma unroll
    for (int mask = 32; mask >= 1; mask >>= 1) m = fmaxf(m, __shfl_xor(m, mask, 64));
    float p = (lane < 40) ? expf(val - m) : 0.f;
    float s = p;
#pragma unroll
    for (int mask = 32; mask >= 1; mask >>= 1) s += __shfl_xor(s, mask, 64);
    float ls = val - m - logf(s);
    if (lane < 40) out[(size_t)node * 40 + lane] = ls;
    hv = nhv;
  }
}

extern "C" void kernel_launch(void* const* d_in, const int* in_sizes, int n_in,
                              void* d_out, int out_size, void* d_ws, size_t ws_size,
                              hipStream_t stream) {
  const float* x = (const float*)d_in[0];
  const int* esrc = (const int*)d_in[1];
  const int* edst = (const int*)d_in[2];
  const float* ew = (const float*)d_in[3];
  const float* Win = (const float*)d_in[4];
  const float* bin = (const float*)d_in[5];
  const float* convW = (const float*)d_in[6];
  const float* Wout = (const float*)d_in[7];
  const float* bout = (const float*)d_in[8];
  float* out = (float*)d_out;

  const int N = in_sizes[0] / 128;
  const int E = in_sizes[1];
  const int NC = in_sizes[6] / (64 * 64);

  char* ws = (char*)d_ws;
  size_t off = 0;
  auto alloc = [&](size_t b) {
    void* p = ws + off;
    off += (b + 255) & ~(size_t)255;
    return p;
  };
  float* x0 = (float*)alloc((size_t)N * 64 * 4);
  float* ha = (float*)alloc((size_t)N * 64 * 4);
  float* hb = (float*)alloc((size_t)N * 64 * 4);
  int* deg = (int*)alloc((size_t)N * 4);
  int* rp = (int*)alloc((size_t)(N + 1) * 4);
  int* cur = (int*)alloc((size_t)N * 4);
  int* bsum = (int*)alloc(1024);
  int2* edge = (int2*)alloc((size_t)E * 8);

  hipMemsetAsync(deg, 0, (size_t)N * 4, stream);
  hist_k<<<2048, 256, 0, stream>>>(edst, deg, E);
  int nb = (N + 1023) / 1024;
  scan1_k<<<nb, 1024, 0, stream>>>(deg, rp, bsum, N);
  scan2_k<<<1, 256, 0, stream>>>(bsum, nb);
  scan3_k<<<nb, 1024, 0, stream>>>(rp, cur, bsum, N, E);
  scatter_k<<<2048, 256, 0, stream>>>(esrc, edst, ew, cur, edge, E);

  ingemm_k<<<2048, 256, 0, stream>>>(x, Win, bin, x0, N);

  const float* hin = x0;
  float* bufs[2] = {ha, hb};
  for (int l = 0; l < NC; ++l) {
    float beta = logf(0.5f / (float)(l + 1) + 1.0f);
    float* ho = bufs[l & 1];
    layer_k<<<2048, 256, 0, stream>>>((const float4*)hin, x0, rp, edge, convW + (size_t)l * 64 * 64, ho, beta, N);
    hin = ho;
  }
  out_k<<<2048, 256, 0, stream>>>(hin, Wout, bout, out, N);
}

// Round 4
// 918.762 us; speedup vs baseline: 1.1053x; 1.1053x over previous
//
#include <hip/hip_runtime.h>
#include <math.h>

typedef _Float16 f16x8 __attribute__((ext_vector_type(8)));
typedef float f32x4 __attribute__((ext_vector_type(4)));

__device__ __forceinline__ float us2f(unsigned short u) {
  _Float16 h;
  __builtin_memcpy(&h, &u, 2);
  return (float)h;
}
__device__ __forceinline__ unsigned short f2us(float f) {
  _Float16 h = (_Float16)f;
  unsigned short u;
  __builtin_memcpy(&u, &h, 2);
  return u;
}

// Wave-uniform broadcast of lane k's value
__device__ __forceinline__ float bcast(float v, int k) {
  return __int_as_float(__builtin_amdgcn_readlane(__float_as_int(v), k));
}

// ---------------- CSR build ----------------
__global__ __launch_bounds__(256) void hist_k(const int* __restrict__ dst, int* __restrict__ deg, int E) {
  for (int e = blockIdx.x * blockDim.x + threadIdx.x; e < E; e += gridDim.x * blockDim.x)
    atomicAdd(&deg[dst[e]], 1);
}

__global__ __launch_bounds__(1024) void scan1_k(const int* __restrict__ deg, int* __restrict__ rp,
                                                int* __restrict__ bsum, int n) {
  __shared__ int buf[2][1024];
  int tid = threadIdx.x;
  int i = blockIdx.x * 1024 + tid;
  int v = (i < n) ? deg[i] : 0;
  int pp = 0;
  buf[0][tid] = v;
  __syncthreads();
  for (int off = 1; off < 1024; off <<= 1) {
    int t = buf[pp][tid];
    if (tid >= off) t += buf[pp][tid - off];
    buf[pp ^ 1][tid] = t;
    pp ^= 1;
    __syncthreads();
  }
  int inc = buf[pp][tid];
  if (i < n) rp[i] = inc - v;
  if (tid == 1023) bsum[blockIdx.x] = inc;
}

__global__ __launch_bounds__(256) void scan2_k(int* __restrict__ bsum, int nb) {
  __shared__ int buf[2][256];
  int tid = threadIdx.x;
  int v = (tid < nb) ? bsum[tid] : 0;
  int pp = 0;
  buf[0][tid] = v;
  __syncthreads();
  for (int off = 1; off < 256; off <<= 1) {
    int t = buf[pp][tid];
    if (tid >= off) t += buf[pp][tid - off];
    buf[pp ^ 1][tid] = t;
    pp ^= 1;
    __syncthreads();
  }
  if (tid < nb) bsum[tid] = buf[pp][tid] - v;
}

__global__ __launch_bounds__(1024) void scan3_k(int* __restrict__ rp, int* __restrict__ cur,
                                                const int* __restrict__ bsum, int n, int E) {
  int i = blockIdx.x * 1024 + threadIdx.x;
  if (i < n) {
    int v = rp[i] + bsum[blockIdx.x];
    rp[i] = v;
    cur[i] = v;
  }
  if (i == 0) rp[n] = E;
}

__global__ __launch_bounds__(256) void scatter_k(const int* __restrict__ src, const int* __restrict__ dst,
                                                 const float* __restrict__ w, int* __restrict__ cur,
                                                 int2* __restrict__ edge, int E) {
  for (int e = blockIdx.x * blockDim.x + threadIdx.x; e < E; e += gridDim.x * blockDim.x) {
    int d = dst[e];
    int pos = atomicAdd(&cur[d], 1);
    edge[pos] = make_int2(src[e], __float_as_int(w[e]));
  }
}

// ---------------- x0 = relu(x @ W_in + b_in)  [MFMA, fp16 out] ----------------
// 16 nodes per wave. A: lane l holds x[node_base + (l&15)][c*32 + (l>>4)*8 + j].
// B: lane l holds W[c*32 + (l>>4)*8 + j][t*16 + (l&15)].
// D (verified): col = lane&15, row = (lane>>4)*4 + reg.
__global__ __launch_bounds__(256) void ingemm_k(const float* __restrict__ x, const float* __restrict__ Win,
                                                const float* __restrict__ bin, unsigned short* __restrict__ x0,
                                                int n) {
  int lane = threadIdx.x & 63;
  int wave = threadIdx.x >> 6;
  int col = lane & 15, grp = lane >> 4;
  f16x8 B[4][4];
#pragma unroll
  for (int c = 0; c < 4; ++c)
#pragma unroll
    for (int t = 0; t < 4; ++t) {
      f16x8 b;
#pragma unroll
      for (int j = 0; j < 8; ++j) b[j] = (_Float16)Win[(c * 32 + grp * 8 + j) * 64 + t * 16 + col];
      B[c][t] = b;
    }
  float bb[4];
#pragma unroll
  for (int t = 0; t < 4; ++t) bb[t] = bin[t * 16 + col];

  int node_base = (blockIdx.x * 4 + wave) * 16;
  if (node_base >= n) return;
  int arow = node_base + col;
  if (arow > n - 1) arow = n - 1;
  const float* xr = x + (size_t)arow * 128 + grp * 8;

  f32x4 acc[4];
  f32x4 z = {0.f, 0.f, 0.f, 0.f};
#pragma unroll
  for (int t = 0; t < 4; ++t) acc[t] = z;
#pragma unroll
  for (int c = 0; c < 4; ++c) {
    f32x4 lo = *(const f32x4*)(xr + c * 32);
    f32x4 hi = *(const f32x4*)(xr + c * 32 + 4);
    f16x8 a;
#pragma unroll
    for (int j = 0; j < 4; ++j) a[j] = (_Float16)lo[j];
#pragma unroll
    for (int j = 0; j < 4; ++j) a[4 + j] = (_Float16)hi[j];
#pragma unroll
    for (int t = 0; t < 4; ++t) acc[t] = __builtin_amdgcn_mfma_f32_16x16x32_f16(a, B[c][t], acc[t], 0, 0, 0);
  }
#pragma unroll
  for (int t = 0; t < 4; ++t)
#pragma unroll
    for (int r = 0; r < 4; ++r) {
      int node = node_base + grp * 4 + r;
      if (node < n) {
        float o = acc[t][r] + bb[t];
        x0[(size_t)node * 64 + t * 16 + col] = f2us(fmaxf(o, 0.f));
      }
    }
}

// ---------------- SpMM: hh = 0.9 * (A @ h) + 0.1 * x0  [fp16 in/out] ----------------
// One wave per node, lane = feature. One coalesced 128B row load per edge.
__global__ __launch_bounds__(256) void spmm_k(const unsigned short* __restrict__ hin,
                                              const unsigned short* __restrict__ x0,
                                              const int* __restrict__ rp, const int2* __restrict__ edge,
                                              unsigned short* __restrict__ hh, int n) {
  int lane = threadIdx.x & 63;
  int wave = threadIdx.x >> 6;
  int S = gridDim.x * 4;
  for (int node = blockIdx.x * 4 + wave; node < n; node += S) {
    int beg = rp[node], end = rp[node + 1];
    float acc0 = 0.f, acc1 = 0.f;
    int e = beg;
    for (; e + 1 < end; e += 2) {
      int2 e0 = edge[e];
      int2 e1 = edge[e + 1];
      float v0 = us2f(hin[(size_t)e0.x * 64 + lane]);
      float v1 = us2f(hin[(size_t)e1.x * 64 + lane]);
      acc0 = fmaf(v0, __int_as_float(e0.y), acc0);
      acc1 = fmaf(v1, __int_as_float(e1.y), acc1);
    }
    if (e < end) {
      int2 e0 = edge[e];
      acc0 = fmaf(us2f(hin[(size_t)e0.x * 64 + lane]), __int_as_float(e0.y), acc0);
    }
    float hhv = fmaf(0.9f, acc0 + acc1, 0.1f * us2f(x0[(size_t)node * 64 + lane]));
    hh[(size_t)node * 64 + lane] = f2us(hhv);
  }
}

// ---------------- h = relu((1-beta)*hh + beta*(hh @ W))  [MFMA, fp16] ----------------
__global__ __launch_bounds__(256) void gemm_k(const unsigned short* __restrict__ hh,
                                              const float* __restrict__ W, unsigned short* __restrict__ hout,
                                              float beta, int n) {
  int lane = threadIdx.x & 63;
  int wave = threadIdx.x >> 6;
  int col = lane & 15, grp = lane >> 4;
  f16x8 B[2][4];
#pragma unroll
  for (int c = 0; c < 2; ++c)
#pragma unroll
    for (int t = 0; t < 4; ++t) {
      f16x8 b;
#pragma unroll
      for (int j = 0; j < 8; ++j) b[j] = (_Float16)W[(c * 32 + grp * 8 + j) * 64 + t * 16 + col];
      B[c][t] = b;
    }
  int node_base = (blockIdx.x * 4 + wave) * 16;
  if (node_base >= n) return;
  int arow = node_base + col;
  if (arow > n - 1) arow = n - 1;
  const unsigned short* rowp = hh + (size_t)arow * 64 + grp * 8;
  f16x8 A0 = *(const f16x8*)(rowp);       // k = grp*8 + j       (chunk 0)
  f16x8 A1 = *(const f16x8*)(rowp + 32);  // k = 32 + grp*8 + j  (chunk 1)

  f32x4 acc[4];
  f32x4 z = {0.f, 0.f, 0.f, 0.f};
#pragma unroll
  for (int t = 0; t < 4; ++t) acc[t] = z;
#pragma unroll
  for (int t = 0; t < 4; ++t) {
    acc[t] = __builtin_amdgcn_mfma_f32_16x16x32_f16(A0, B[0][t], acc[t], 0, 0, 0);
    acc[t] = __builtin_amdgcn_mfma_f32_16x16x32_f16(A1, B[1][t], acc[t], 0, 0, 0);
  }
  float ob = 1.f - beta;
#pragma unroll
  for (int t = 0; t < 4; ++t)
#pragma unroll
    for (int r = 0; r < 4; ++r) {
      int node = node_base + grp * 4 + r;
      if (node < n) {
        float hv = us2f(hh[(size_t)node * 64 + t * 16 + col]);
        float o = ob * hv + beta * acc[t][r];
        hout[(size_t)node * 64 + t * 16 + col] = f2us(fmaxf(o, 0.f));
      }
    }
}

// ---------------- out = log_softmax(h @ W_out + b_out)  [fp16 in, f32 out] ----------------
__global__ __launch_bounds__(256) void out_k(const unsigned short* __restrict__ h,
                                             const float* __restrict__ Wout, const float* __restrict__ bout,
                                             float* __restrict__ out, int n) {
  int lane = threadIdx.x & 63;
  int wave = threadIdx.x >> 6;
  int S = gridDim.x * 4;
  float Wreg[64];
#pragma unroll
  for (int k = 0; k < 64; ++k) Wreg[k] = (lane < 40) ? Wout[k * 40 + lane] : 0.f;
  float bb = (lane < 40) ? bout[lane] : 0.f;
  int node = blockIdx.x * 4 + wave;
  if (node >= n) return;
  float hv = us2f(h[(size_t)node * 64 + lane]);
  for (; node < n; node += S) {
    int nn = node + S;
    float nhv = (nn < n) ? us2f(h[(size_t)nn * 64 + lane]) : 0.f;
    float d0 = 0.f, d1 = 0.f;
#pragma unroll
    for (int k = 0; k < 64; k += 2) {
      d0 = fmaf(bcast(hv, k), Wreg[k], d0);
      d1 = fmaf(bcast(hv, k + 1), Wreg[k + 1], d1);
    }
    float val = (lane < 40) ? (d0 + d1 + bb) : -INFINITY;
    float m = val;
#pragma unroll
    for (int mask = 32; mask >= 1; mask >>= 1) m = fmaxf(m, __shfl_xor(m, mask, 64));
    float p = (lane < 40) ? expf(val - m) : 0.f;
    float s = p;
#pragma unroll
    for (int mask = 32; mask >= 1; mask >>= 1) s += __shfl_xor(s, mask, 64);
    float ls = val - m - logf(s);
    if (lane < 40) out[(size_t)node * 40 + lane] = ls;
    hv = nhv;
  }
}

extern "C" void kernel_launch(void* const* d_in, const int* in_sizes, int n_in,
                              void* d_out, int out_size, void* d_ws, size_t ws_size,
                              hipStream_t stream) {
  const float* x = (const float*)d_in[0];
  const int* esrc = (const int*)d_in[1];
  const int* edst = (const int*)d_in[2];
  const float* ew = (const float*)d_in[3];
  const float* Win = (const float*)d_in[4];
  const float* bin = (const float*)d_in[5];
  const float* convW = (const float*)d_in[6];
  const float* Wout = (const float*)d_in[7];
  const float* bout = (const float*)d_in[8];
  float* out = (float*)d_out;

  const int N = in_sizes[0] / 128;
  const int E = in_sizes[1];
  const int NC = in_sizes[6] / (64 * 64);

  char* ws = (char*)d_ws;
  size_t off = 0;
  auto alloc = [&](size_t b) {
    void* p = ws + off;
    off += (b + 255) & ~(size_t)255;
    return p;
  };
  unsigned short* x0 = (unsigned short*)alloc((size_t)N * 64 * 2);
  unsigned short* ha = (unsigned short*)alloc((size_t)N * 64 * 2);
  unsigned short* hb = (unsigned short*)alloc((size_t)N * 64 * 2);
  unsigned short* hhb = (unsigned short*)alloc((size_t)N * 64 * 2);
  int* deg = (int*)alloc((size_t)N * 4);
  int* rp = (int*)alloc((size_t)(N + 1) * 4);
  int* cur = (int*)alloc((size_t)N * 4);
  int* bsum = (int*)alloc(1024);
  int2* edge = (int2*)alloc((size_t)E * 8);

  hipMemsetAsync(deg, 0, (size_t)N * 4, stream);
  hist_k<<<2048, 256, 0, stream>>>(edst, deg, E);
  int nb = (N + 1023) / 1024;
  scan1_k<<<nb, 1024, 0, stream>>>(deg, rp, bsum, N);
  scan2_k<<<1, 256, 0, stream>>>(bsum, nb);
  scan3_k<<<nb, 1024, 0, stream>>>(rp, cur, bsum, N, E);
  scatter_k<<<2048, 256, 0, stream>>>(esrc, edst, ew, cur, edge, E);

  int gblocks = (N + 63) / 64;
  ingemm_k<<<gblocks, 256, 0, stream>>>(x, Win, bin, x0, N);

  const unsigned short* hin = x0;
  unsigned short* bufs[2] = {ha, hb};
  for (int l = 0; l < NC; ++l) {
    float beta = logf(0.5f / (float)(l + 1) + 1.0f);
    unsigned short* ho = bufs[l & 1];
    spmm_k<<<2048, 256, 0, stream>>>(hin, x0, rp, edge, hhb, N);
    gemm_k<<<gblocks, 256, 0, stream>>>(hhb, convW + (size_t)l * 64 * 64, ho, beta, N);
    hin = ho;
  }
  out_k<<<2048, 256, 0, stream>>>(hin, Wout, bout, out, N);
}

// Round 5
// 668.920 us; speedup vs baseline: 1.5182x; 1.3735x over previous
//
#include <hip/hip_runtime.h>
#include <math.h>

typedef _Float16 f16x8 __attribute__((ext_vector_type(8)));
typedef float f32x4 __attribute__((ext_vector_type(4)));

__device__ __forceinline__ float us2f(unsigned short u) {
  _Float16 h;
  __builtin_memcpy(&h, &u, 2);
  return (float)h;
}
__device__ __forceinline__ unsigned short f2us(float f) {
  _Float16 h = (_Float16)f;
  unsigned short u;
  __builtin_memcpy(&u, &h, 2);
  return u;
}

// Wave-uniform broadcast of lane k's value
__device__ __forceinline__ float bcast(float v, int k) {
  return __int_as_float(__builtin_amdgcn_readlane(__float_as_int(v), k));
}

// ---------------- CSR build: histogram (XCD-partitioned dst ranges) ----------------
__global__ __launch_bounds__(256) void hist_k(const int* __restrict__ dst, int* __restrict__ deg,
                                              int E, int N) {
  int xcd = blockIdx.x & 7;
  int bid = blockIdx.x >> 3;
  int nb = gridDim.x >> 3;
  int R = (N + 7) >> 3;
  int lo = xcd * R;
  int hi = min(N, lo + R);
  for (int e = bid * blockDim.x + threadIdx.x; e < E; e += nb * blockDim.x) {
    int d = dst[e];
    if (d >= lo && d < hi) atomicAdd(&deg[d], 1);
  }
}

// ---------------- CSR build: 3-kernel exclusive scan ----------------
__global__ __launch_bounds__(1024) void scan1_k(const int* __restrict__ deg, int* __restrict__ rp,
                                                int* __restrict__ bsum, int n) {
  __shared__ int buf[2][1024];
  int tid = threadIdx.x;
  int i = blockIdx.x * 1024 + tid;
  int v = (i < n) ? deg[i] : 0;
  int pp = 0;
  buf[0][tid] = v;
  __syncthreads();
  for (int off = 1; off < 1024; off <<= 1) {
    int t = buf[pp][tid];
    if (tid >= off) t += buf[pp][tid - off];
    buf[pp ^ 1][tid] = t;
    pp ^= 1;
    __syncthreads();
  }
  int inc = buf[pp][tid];
  if (i < n) rp[i] = inc - v;
  if (tid == 1023) bsum[blockIdx.x] = inc;
}

__global__ __launch_bounds__(256) void scan2_k(int* __restrict__ bsum, int nb) {
  __shared__ int buf[2][256];
  int tid = threadIdx.x;
  int v = (tid < nb) ? bsum[tid] : 0;
  int pp = 0;
  buf[0][tid] = v;
  __syncthreads();
  for (int off = 1; off < 256; off <<= 1) {
    int t = buf[pp][tid];
    if (tid >= off) t += buf[pp][tid - off];
    buf[pp ^ 1][tid] = t;
    pp ^= 1;
    __syncthreads();
  }
  if (tid < nb) bsum[tid] = buf[pp][tid] - v;
}

__global__ __launch_bounds__(1024) void scan3_k(int* __restrict__ rp, int* __restrict__ cur,
                                                const int* __restrict__ bsum, int n, int E) {
  int i = blockIdx.x * 1024 + threadIdx.x;
  if (i < n) {
    int v = rp[i] + bsum[blockIdx.x];
    rp[i] = v;
    cur[i] = v;
  }
  if (i == 0) rp[n] = E;
}

// ---------------- CSR build: counting-sort scatter (XCD-partitioned dst ranges) ----------------
// All writes to a given CSR region come from one XCD -> 8B writes merge to full
// lines in that XCD's L2 before eviction.
__global__ __launch_bounds__(256) void scatter_k(const int* __restrict__ src, const int* __restrict__ dst,
                                                 const float* __restrict__ w, int* __restrict__ cur,
                                                 int2* __restrict__ edge, int E, int N) {
  int xcd = blockIdx.x & 7;
  int bid = blockIdx.x >> 3;
  int nb = gridDim.x >> 3;
  int R = (N + 7) >> 3;
  int lo = xcd * R;
  int hi = min(N, lo + R);
  for (int e = bid * blockDim.x + threadIdx.x; e < E; e += nb * blockDim.x) {
    int d = dst[e];
    if (d >= lo && d < hi) {
      int pos = atomicAdd(&cur[d], 1);
      edge[pos] = make_int2(src[e], __float_as_int(w[e]));
    }
  }
}

// ---------------- x0 = relu(x @ W_in + b_in)  [MFMA, fp16 out] ----------------
__global__ __launch_bounds__(256) void ingemm_k(const float* __restrict__ x, const float* __restrict__ Win,
                                                const float* __restrict__ bin, unsigned short* __restrict__ x0,
                                                int n) {
  int lane = threadIdx.x & 63;
  int wave = threadIdx.x >> 6;
  int col = lane & 15, grp = lane >> 4;
  f16x8 B[4][4];
#pragma unroll
  for (int c = 0; c < 4; ++c)
#pragma unroll
    for (int t = 0; t < 4; ++t) {
      f16x8 b;
#pragma unroll
      for (int j = 0; j < 8; ++j) b[j] = (_Float16)Win[(c * 32 + grp * 8 + j) * 64 + t * 16 + col];
      B[c][t] = b;
    }
  float bb[4];
#pragma unroll
  for (int t = 0; t < 4; ++t) bb[t] = bin[t * 16 + col];

  int node_base = (blockIdx.x * 4 + wave) * 16;
  if (node_base >= n) return;
  int arow = node_base + col;
  if (arow > n - 1) arow = n - 1;
  const float* xr = x + (size_t)arow * 128 + grp * 8;

  f32x4 acc[4];
  f32x4 z = {0.f, 0.f, 0.f, 0.f};
#pragma unroll
  for (int t = 0; t < 4; ++t) acc[t] = z;
#pragma unroll
  for (int c = 0; c < 4; ++c) {
    f32x4 lo = *(const f32x4*)(xr + c * 32);
    f32x4 hi = *(const f32x4*)(xr + c * 32 + 4);
    f16x8 a;
#pragma unroll
    for (int j = 0; j < 4; ++j) a[j] = (_Float16)lo[j];
#pragma unroll
    for (int j = 0; j < 4; ++j) a[4 + j] = (_Float16)hi[j];
#pragma unroll
    for (int t = 0; t < 4; ++t) acc[t] = __builtin_amdgcn_mfma_f32_16x16x32_f16(a, B[c][t], acc[t], 0, 0, 0);
  }
#pragma unroll
  for (int t = 0; t < 4; ++t)
#pragma unroll
    for (int r = 0; r < 4; ++r) {
      int node = node_base + grp * 4 + r;
      if (node < n) {
        float o = acc[t][r] + bb[t];
        x0[(size_t)node * 64 + t * 16 + col] = f2us(fmaxf(o, 0.f));
      }
    }
}

// ---------------- SpMM: hh = 0.9 * (A @ h) + 0.1 * x0  [fp16, 2 nodes/wave, 8-edge batches] ----------------
__global__ __launch_bounds__(256) void spmm_k(const ushort2* __restrict__ hin2,
                                              const ushort2* __restrict__ x02,
                                              const int* __restrict__ rp, const int2* __restrict__ edge,
                                              ushort2* __restrict__ hh2, int n) {
  int lane = threadIdx.x & 63;
  int wave = threadIdx.x >> 6;
  int half = lane >> 5;  // node selector within wave
  int sl = lane & 31;    // feature pair 0..31
  int S = gridDim.x * 8;
  for (int node = (blockIdx.x * 4 + wave) * 2 + half; node < n; node += S) {
    int beg = rp[node], end = rp[node + 1];
    ushort2 xv = x02[(size_t)node * 32 + sl];
    float ax = 0.f, ay = 0.f;
    for (int e = beg; e < end; e += 8) {
      int2 d[8];
#pragma unroll
      for (int j = 0; j < 8; ++j) d[j] = (e + j < end) ? edge[e + j] : make_int2(0, 0);
      ushort2 v[8];
#pragma unroll
      for (int j = 0; j < 8; ++j) v[j] = hin2[(size_t)d[j].x * 32 + sl];
#pragma unroll
      for (int j = 0; j < 8; ++j) {
        float w = __int_as_float(d[j].y);
        ax = fmaf(us2f(v[j].x), w, ax);
        ay = fmaf(us2f(v[j].y), w, ay);
      }
    }
    float hx = fmaf(0.9f, ax, 0.1f * us2f(xv.x));
    float hy = fmaf(0.9f, ay, 0.1f * us2f(xv.y));
    ushort2 o;
    o.x = f2us(hx);
    o.y = f2us(hy);
    hh2[(size_t)node * 32 + sl] = o;
  }
}

// ---------------- h = relu((1-beta)*hh + beta*(hh @ W))  [MFMA, fp16] ----------------
__global__ __launch_bounds__(256) void gemm_k(const unsigned short* __restrict__ hh,
                                              const float* __restrict__ W, unsigned short* __restrict__ hout,
                                              float beta, int n) {
  int lane = threadIdx.x & 63;
  int wave = threadIdx.x >> 6;
  int col = lane & 15, grp = lane >> 4;
  f16x8 B[2][4];
#pragma unroll
  for (int c = 0; c < 2; ++c)
#pragma unroll
    for (int t = 0; t < 4; ++t) {
      f16x8 b;
#pragma unroll
      for (int j = 0; j < 8; ++j) b[j] = (_Float16)W[(c * 32 + grp * 8 + j) * 64 + t * 16 + col];
      B[c][t] = b;
    }
  int node_base = (blockIdx.x * 4 + wave) * 16;
  if (node_base >= n) return;
  int arow = node_base + col;
  if (arow > n - 1) arow = n - 1;
  const unsigned short* rowp = hh + (size_t)arow * 64 + grp * 8;
  f16x8 A0 = *(const f16x8*)(rowp);
  f16x8 A1 = *(const f16x8*)(rowp + 32);

  f32x4 acc[4];
  f32x4 z = {0.f, 0.f, 0.f, 0.f};
#pragma unroll
  for (int t = 0; t < 4; ++t) acc[t] = z;
#pragma unroll
  for (int t = 0; t < 4; ++t) {
    acc[t] = __builtin_amdgcn_mfma_f32_16x16x32_f16(A0, B[0][t], acc[t], 0, 0, 0);
    acc[t] = __builtin_amdgcn_mfma_f32_16x16x32_f16(A1, B[1][t], acc[t], 0, 0, 0);
  }
  float ob = 1.f - beta;
#pragma unroll
  for (int t = 0; t < 4; ++t)
#pragma unroll
    for (int r = 0; r < 4; ++r) {
      int node = node_base + grp * 4 + r;
      if (node < n) {
        float hv = us2f(hh[(size_t)node * 64 + t * 16 + col]);
        float o = ob * hv + beta * acc[t][r];
        hout[(size_t)node * 64 + t * 16 + col] = f2us(fmaxf(o, 0.f));
      }
    }
}

// ---------------- out = log_softmax(h @ W_out + b_out)  [fp16 in, f32 out] ----------------
__global__ __launch_bounds__(256) void out_k(const unsigned short* __restrict__ h,
                                             const float* __restrict__ Wout, const float* __restrict__ bout,
                                             float* __restrict__ out, int n) {
  int lane = threadIdx.x & 63;
  int wave = threadIdx.x >> 6;
  int S = gridDim.x * 4;
  float Wreg[64];
#pragma unroll
  for (int k = 0; k < 64; ++k) Wreg[k] = (lane < 40) ? Wout[k * 40 + lane] : 0.f;
  float bb = (lane < 40) ? bout[lane] : 0.f;
  int node = blockIdx.x * 4 + wave;
  if (node >= n) return;
  float hv = us2f(h[(size_t)node * 64 + lane]);
  for (; node < n; node += S) {
    int nn = node + S;
    float nhv = (nn < n) ? us2f(h[(size_t)nn * 64 + lane]) : 0.f;
    float d0 = 0.f, d1 = 0.f;
#pragma unroll
    for (int k = 0; k < 64; k += 2) {
      d0 = fmaf(bcast(hv, k), Wreg[k], d0);
      d1 = fmaf(bcast(hv, k + 1), Wreg[k + 1], d1);
    }
    float val = (lane < 40) ? (d0 + d1 + bb) : -INFINITY;
    float m = val;
#pragma unroll
    for (int mask = 32; mask >= 1; mask >>= 1) m = fmaxf(m, __shfl_xor(m, mask, 64));
    float p = (lane < 40) ? expf(val - m) : 0.f;
    float s = p;
#pragma unroll
    for (int mask = 32; mask >= 1; mask >>= 1) s += __shfl_xor(s, mask, 64);
    float ls = val - m - logf(s);
    if (lane < 40) out[(size_t)node * 40 + lane] = ls;
    hv = nhv;
  }
}

extern "C" void kernel_launch(void* const* d_in, const int* in_sizes, int n_in,
                              void* d_out, int out_size, void* d_ws, size_t ws_size,
                              hipStream_t stream) {
  const float* x = (const float*)d_in[0];
  const int* esrc = (const int*)d_in[1];
  const int* edst = (const int*)d_in[2];
  const float* ew = (const float*)d_in[3];
  const float* Win = (const float*)d_in[4];
  const float* bin = (const float*)d_in[5];
  const float* convW = (const float*)d_in[6];
  const float* Wout = (const float*)d_in[7];
  const float* bout = (const float*)d_in[8];
  float* out = (float*)d_out;

  const int N = in_sizes[0] / 128;
  const int E = in_sizes[1];
  const int NC = in_sizes[6] / (64 * 64);

  char* ws = (char*)d_ws;
  size_t off = 0;
  auto alloc = [&](size_t b) {
    void* p = ws + off;
    off += (b + 255) & ~(size_t)255;
    return p;
  };
  unsigned short* x0 = (unsigned short*)alloc((size_t)N * 64 * 2);
  unsigned short* ha = (unsigned short*)alloc((size_t)N * 64 * 2);
  unsigned short* hb = (unsigned short*)alloc((size_t)N * 64 * 2);
  unsigned short* hhb = (unsigned short*)alloc((size_t)N * 64 * 2);
  int* deg = (int*)alloc((size_t)N * 4);
  int* rp = (int*)alloc((size_t)(N + 1) * 4);
  int* cur = (int*)alloc((size_t)N * 4);
  int* bsum = (int*)alloc(1024);
  int2* edge = (int2*)alloc((size_t)E * 8);

  hipMemsetAsync(deg, 0, (size_t)N * 4, stream);
  hist_k<<<2048, 256, 0, stream>>>(edst, deg, E, N);
  int nb = (N + 1023) / 1024;
  scan1_k<<<nb, 1024, 0, stream>>>(deg, rp, bsum, N);
  scan2_k<<<1, 256, 0, stream>>>(bsum, nb);
  scan3_k<<<nb, 1024, 0, stream>>>(rp, cur, bsum, N, E);
  scatter_k<<<2048, 256, 0, stream>>>(esrc, edst, ew, cur, edge, E, N);

  int gblocks = (N + 63) / 64;
  ingemm_k<<<gblocks, 256, 0, stream>>>(x, Win, bin, x0, N);

  const unsigned short* hin = x0;
  unsigned short* bufs[2] = {ha, hb};
  for (int l = 0; l < NC; ++l) {
    float beta = logf(0.5f / (float)(l + 1) + 1.0f);
    unsigned short* ho = bufs[l & 1];
    spmm_k<<<2048, 256, 0, stream>>>((const ushort2*)hin, (const ushort2*)x0, rp, edge, (ushort2*)hhb, N);
    gemm_k<<<gblocks, 256, 0, stream>>>(hhb, convW + (size_t)l * 64 * 64, ho, beta, N);
    hin = ho;
  }
  out_k<<<2048, 256, 0, stream>>>(hin, Wout, bout, out, N);
}

// Round 6
// 561.686 us; speedup vs baseline: 1.8080x; 1.1909x over previous
//
#include <hip/hip_runtime.h>
#include <math.h>

typedef _Float16 f16x8 __attribute__((ext_vector_type(8)));
typedef float f32x4 __attribute__((ext_vector_type(4)));

__device__ __forceinline__ float us2f(unsigned short u) {
  _Float16 h;
  __builtin_memcpy(&h, &u, 2);
  return (float)h;
}
__device__ __forceinline__ unsigned short f2us(float f) {
  _Float16 h = (_Float16)f;
  unsigned short u;
  __builtin_memcpy(&u, &h, 2);
  return u;
}

// ---------------- CSR build: histogram (XCD-partitioned dst ranges) ----------------
__global__ __launch_bounds__(256) void hist_k(const int* __restrict__ dst, int* __restrict__ deg,
                                              int E, int N) {
  int xcd = blockIdx.x & 7;
  int bid = blockIdx.x >> 3;
  int nb = gridDim.x >> 3;
  int R = (N + 7) >> 3;
  int lo = xcd * R;
  int hi = min(N, lo + R);
  for (int e = bid * blockDim.x + threadIdx.x; e < E; e += nb * blockDim.x) {
    int d = dst[e];
    if (d >= lo && d < hi) atomicAdd(&deg[d], 1);
  }
}

// ---------------- CSR build: 3-kernel exclusive scan ----------------
__global__ __launch_bounds__(1024) void scan1_k(const int* __restrict__ deg, int* __restrict__ rp,
                                                int* __restrict__ bsum, int n) {
  __shared__ int buf[2][1024];
  int tid = threadIdx.x;
  int i = blockIdx.x * 1024 + tid;
  int v = (i < n) ? deg[i] : 0;
  int pp = 0;
  buf[0][tid] = v;
  __syncthreads();
  for (int off = 1; off < 1024; off <<= 1) {
    int t = buf[pp][tid];
    if (tid >= off) t += buf[pp][tid - off];
    buf[pp ^ 1][tid] = t;
    pp ^= 1;
    __syncthreads();
  }
  int inc = buf[pp][tid];
  if (i < n) rp[i] = inc - v;
  if (tid == 1023) bsum[blockIdx.x] = inc;
}

__global__ __launch_bounds__(256) void scan2_k(int* __restrict__ bsum, int nb) {
  __shared__ int buf[2][256];
  int tid = threadIdx.x;
  int v = (tid < nb) ? bsum[tid] : 0;
  int pp = 0;
  buf[0][tid] = v;
  __syncthreads();
  for (int off = 1; off < 256; off <<= 1) {
    int t = buf[pp][tid];
    if (tid >= off) t += buf[pp][tid - off];
    buf[pp ^ 1][tid] = t;
    pp ^= 1;
    __syncthreads();
  }
  if (tid < nb) bsum[tid] = buf[pp][tid] - v;
}

__global__ __launch_bounds__(1024) void scan3_k(int* __restrict__ rp, int* __restrict__ cur,
                                                const int* __restrict__ bsum, int n, int E) {
  int i = blockIdx.x * 1024 + threadIdx.x;
  if (i < n) {
    int v = rp[i] + bsum[blockIdx.x];
    rp[i] = v;
    cur[i] = v;
  }
  if (i == 0) rp[n] = E;
}

// ---------------- CSR build: counting-sort scatter (XCD-partitioned dst ranges) ----------------
__global__ __launch_bounds__(256) void scatter_k(const int* __restrict__ src, const int* __restrict__ dst,
                                                 const float* __restrict__ w, int* __restrict__ cur,
                                                 int2* __restrict__ edge, int E, int N) {
  int xcd = blockIdx.x & 7;
  int bid = blockIdx.x >> 3;
  int nb = gridDim.x >> 3;
  int R = (N + 7) >> 3;
  int lo = xcd * R;
  int hi = min(N, lo + R);
  for (int e = bid * blockDim.x + threadIdx.x; e < E; e += nb * blockDim.x) {
    int d = dst[e];
    if (d >= lo && d < hi) {
      int pos = atomicAdd(&cur[d], 1);
      edge[pos] = make_int2(src[e], __float_as_int(w[e]));
    }
  }
}

// ---------------- x0 = relu(x @ W_in + b_in)  [MFMA, fp16 out] ----------------
__global__ __launch_bounds__(256) void ingemm_k(const float* __restrict__ x, const float* __restrict__ Win,
                                                const float* __restrict__ bin, unsigned short* __restrict__ x0,
                                                int n) {
  int lane = threadIdx.x & 63;
  int wave = threadIdx.x >> 6;
  int col = lane & 15, grp = lane >> 4;
  f16x8 B[4][4];
#pragma unroll
  for (int c = 0; c < 4; ++c)
#pragma unroll
    for (int t = 0; t < 4; ++t) {
      f16x8 b;
#pragma unroll
      for (int j = 0; j < 8; ++j) b[j] = (_Float16)Win[(c * 32 + grp * 8 + j) * 64 + t * 16 + col];
      B[c][t] = b;
    }
  float bb[4];
#pragma unroll
  for (int t = 0; t < 4; ++t) bb[t] = bin[t * 16 + col];

  int node_base = (blockIdx.x * 4 + wave) * 16;
  if (node_base >= n) return;
  int arow = node_base + col;
  if (arow > n - 1) arow = n - 1;
  const float* xr = x + (size_t)arow * 128 + grp * 8;

  f32x4 acc[4];
  f32x4 z = {0.f, 0.f, 0.f, 0.f};
#pragma unroll
  for (int t = 0; t < 4; ++t) acc[t] = z;
#pragma unroll
  for (int c = 0; c < 4; ++c) {
    f32x4 lo = *(const f32x4*)(xr + c * 32);
    f32x4 hi = *(const f32x4*)(xr + c * 32 + 4);
    f16x8 a;
#pragma unroll
    for (int j = 0; j < 4; ++j) a[j] = (_Float16)lo[j];
#pragma unroll
    for (int j = 0; j < 4; ++j) a[4 + j] = (_Float16)hi[j];
#pragma unroll
    for (int t = 0; t < 4; ++t) acc[t] = __builtin_amdgcn_mfma_f32_16x16x32_f16(a, B[c][t], acc[t], 0, 0, 0);
  }
#pragma unroll
  for (int t = 0; t < 4; ++t)
#pragma unroll
    for (int r = 0; r < 4; ++r) {
      int node = node_base + grp * 4 + r;
      if (node < n) {
        float o = acc[t][r] + bb[t];
        x0[(size_t)node * 64 + t * 16 + col] = f2us(fmaxf(o, 0.f));
      }
    }
}

// ---------------- SpMM: hh = 0.9 * (A @ h) + 0.1 * x0  [fp16, 4 nodes/wave, 8-edge batches] ----------------
// 16-lane groups: lane covers 4 features (ushort4, 8B); 16 lanes x 8B = one 128B row.
__global__ __launch_bounds__(256) void spmm_k(const ushort4* __restrict__ hin4,
                                              const ushort4* __restrict__ x04,
                                              const int* __restrict__ rp, const int2* __restrict__ edge,
                                              ushort4* __restrict__ hh4, int n) {
  int lane = threadIdx.x & 63;
  int wave = threadIdx.x >> 6;
  int q = lane >> 4;   // node slot within wave
  int sl = lane & 15;  // feature quad
  int S = gridDim.x * 16;
  for (int node = (blockIdx.x * 4 + wave) * 4 + q; node < n; node += S) {
    int beg = rp[node], end = rp[node + 1];
    ushort4 xv = x04[(size_t)node * 16 + sl];
    float a0 = 0.f, a1 = 0.f, a2 = 0.f, a3 = 0.f;
    for (int e = beg; e < end; e += 8) {
      int2 d[8];
#pragma unroll
      for (int j = 0; j < 8; ++j) d[j] = (e + j < end) ? edge[e + j] : make_int2(0, 0);
      ushort4 v[8];
#pragma unroll
      for (int j = 0; j < 8; ++j) v[j] = hin4[(size_t)d[j].x * 16 + sl];
#pragma unroll
      for (int j = 0; j < 8; ++j) {
        float w = __int_as_float(d[j].y);
        a0 = fmaf(us2f(v[j].x), w, a0);
        a1 = fmaf(us2f(v[j].y), w, a1);
        a2 = fmaf(us2f(v[j].z), w, a2);
        a3 = fmaf(us2f(v[j].w), w, a3);
      }
    }
    ushort4 o;
    o.x = f2us(fmaf(0.9f, a0, 0.1f * us2f(xv.x)));
    o.y = f2us(fmaf(0.9f, a1, 0.1f * us2f(xv.y)));
    o.z = f2us(fmaf(0.9f, a2, 0.1f * us2f(xv.z)));
    o.w = f2us(fmaf(0.9f, a3, 0.1f * us2f(xv.w)));
    hh4[(size_t)node * 16 + sl] = o;
  }
}

// ---------------- h = relu((1-beta)*hh + beta*(hh @ W))  [MFMA, fp16] ----------------
__global__ __launch_bounds__(256) void gemm_k(const unsigned short* __restrict__ hh,
                                              const float* __restrict__ W, unsigned short* __restrict__ hout,
                                              float beta, int n) {
  int lane = threadIdx.x & 63;
  int wave = threadIdx.x >> 6;
  int col = lane & 15, grp = lane >> 4;
  f16x8 B[2][4];
#pragma unroll
  for (int c = 0; c < 2; ++c)
#pragma unroll
    for (int t = 0; t < 4; ++t) {
      f16x8 b;
#pragma unroll
      for (int j = 0; j < 8; ++j) b[j] = (_Float16)W[(c * 32 + grp * 8 + j) * 64 + t * 16 + col];
      B[c][t] = b;
    }
  int node_base = (blockIdx.x * 4 + wave) * 16;
  if (node_base >= n) return;
  int arow = node_base + col;
  if (arow > n - 1) arow = n - 1;
  const unsigned short* rowp = hh + (size_t)arow * 64 + grp * 8;
  f16x8 A0 = *(const f16x8*)(rowp);
  f16x8 A1 = *(const f16x8*)(rowp + 32);

  f32x4 acc[4];
  f32x4 z = {0.f, 0.f, 0.f, 0.f};
#pragma unroll
  for (int t = 0; t < 4; ++t) acc[t] = z;
#pragma unroll
  for (int t = 0; t < 4; ++t) {
    acc[t] = __builtin_amdgcn_mfma_f32_16x16x32_f16(A0, B[0][t], acc[t], 0, 0, 0);
    acc[t] = __builtin_amdgcn_mfma_f32_16x16x32_f16(A1, B[1][t], acc[t], 0, 0, 0);
  }
  float ob = 1.f - beta;
#pragma unroll
  for (int t = 0; t < 4; ++t)
#pragma unroll
    for (int r = 0; r < 4; ++r) {
      int node = node_base + grp * 4 + r;
      if (node < n) {
        float hv = us2f(hh[(size_t)node * 64 + t * 16 + col]);
        float o = ob * hv + beta * acc[t][r];
        hout[(size_t)node * 64 + t * 16 + col] = f2us(fmaxf(o, 0.f));
      }
    }
}

// ---------------- out = log_softmax(h @ W_out + b_out)  [MFMA, fp16 in, f32 out] ----------------
// 16 nodes/wave; 40 classes in 3 B-tiles (padded to 48). Per node the class row
// lives in 16 lanes (col) x 3 regs (t) -> in-lane reduce over t + 4-step shfl_xor.
__global__ __launch_bounds__(256) void out_k(const unsigned short* __restrict__ h,
                                             const float* __restrict__ Wout, const float* __restrict__ bout,
                                             float* __restrict__ out, int n) {
  int lane = threadIdx.x & 63;
  int wave = threadIdx.x >> 6;
  int col = lane & 15, grp = lane >> 4;
  f16x8 B[2][3];
#pragma unroll
  for (int c = 0; c < 2; ++c)
#pragma unroll
    for (int t = 0; t < 3; ++t) {
      int cls = t * 16 + col;
      f16x8 b;
#pragma unroll
      for (int j = 0; j < 8; ++j) b[j] = (cls < 40) ? (_Float16)Wout[(c * 32 + grp * 8 + j) * 40 + cls] : (_Float16)0.f;
      B[c][t] = b;
    }
  float bb[3];
#pragma unroll
  for (int t = 0; t < 3; ++t) {
    int cls = t * 16 + col;
    bb[t] = (cls < 40) ? bout[cls] : 0.f;
  }
  int node_base = (blockIdx.x * 4 + wave) * 16;
  if (node_base >= n) return;
  int arow = node_base + col;
  if (arow > n - 1) arow = n - 1;
  const unsigned short* rowp = h + (size_t)arow * 64 + grp * 8;
  f16x8 A0 = *(const f16x8*)(rowp);
  f16x8 A1 = *(const f16x8*)(rowp + 32);

  f32x4 acc[3];
  f32x4 z = {0.f, 0.f, 0.f, 0.f};
#pragma unroll
  for (int t = 0; t < 3; ++t) acc[t] = z;
#pragma unroll
  for (int t = 0; t < 3; ++t) {
    acc[t] = __builtin_amdgcn_mfma_f32_16x16x32_f16(A0, B[0][t], acc[t], 0, 0, 0);
    acc[t] = __builtin_amdgcn_mfma_f32_16x16x32_f16(A1, B[1][t], acc[t], 0, 0, 0);
  }
#pragma unroll
  for (int r = 0; r < 4; ++r) {
    int node = node_base + grp * 4 + r;
    float v0 = acc[0][r] + bb[0];
    float v1 = acc[1][r] + bb[1];
    float v2 = (32 + col < 40) ? (acc[2][r] + bb[2]) : -INFINITY;
    float m = fmaxf(fmaxf(v0, v1), v2);
#pragma unroll
    for (int mask = 1; mask <= 8; mask <<= 1) m = fmaxf(m, __shfl_xor(m, mask, 64));
    float p = expf(v0 - m) + expf(v1 - m) + ((32 + col < 40) ? expf(v2 - m) : 0.f);
#pragma unroll
    for (int mask = 1; mask <= 8; mask <<= 1) p += __shfl_xor(p, mask, 64);
    float ml = m + logf(p);
    if (node < n) {
      out[(size_t)node * 40 + col] = v0 - ml;
      out[(size_t)node * 40 + 16 + col] = v1 - ml;
      if (32 + col < 40) out[(size_t)node * 40 + 32 + col] = v2 - ml;
    }
  }
}

extern "C" void kernel_launch(void* const* d_in, const int* in_sizes, int n_in,
                              void* d_out, int out_size, void* d_ws, size_t ws_size,
                              hipStream_t stream) {
  const float* x = (const float*)d_in[0];
  const int* esrc = (const int*)d_in[1];
  const int* edst = (const int*)d_in[2];
  const float* ew = (const float*)d_in[3];
  const float* Win = (const float*)d_in[4];
  const float* bin = (const float*)d_in[5];
  const float* convW = (const float*)d_in[6];
  const float* Wout = (const float*)d_in[7];
  const float* bout = (const float*)d_in[8];
  float* out = (float*)d_out;

  const int N = in_sizes[0] / 128;
  const int E = in_sizes[1];
  const int NC = in_sizes[6] / (64 * 64);

  char* ws = (char*)d_ws;
  size_t off = 0;
  auto alloc = [&](size_t b) {
    void* p = ws + off;
    off += (b + 255) & ~(size_t)255;
    return p;
  };
  unsigned short* x0 = (unsigned short*)alloc((size_t)N * 64 * 2);
  unsigned short* ha = (unsigned short*)alloc((size_t)N * 64 * 2);
  unsigned short* hb = (unsigned short*)alloc((size_t)N * 64 * 2);
  unsigned short* hhb = (unsigned short*)alloc((size_t)N * 64 * 2);
  int* deg = (int*)alloc((size_t)N * 4);
  int* rp = (int*)alloc((size_t)(N + 1) * 4);
  int* cur = (int*)alloc((size_t)N * 4);
  int* bsum = (int*)alloc(1024);
  int2* edge = (int2*)alloc((size_t)E * 8);

  hipMemsetAsync(deg, 0, (size_t)N * 4, stream);
  hist_k<<<2048, 256, 0, stream>>>(edst, deg, E, N);
  int nb = (N + 1023) / 1024;
  scan1_k<<<nb, 1024, 0, stream>>>(deg, rp, bsum, N);
  scan2_k<<<1, 256, 0, stream>>>(bsum, nb);
  scan3_k<<<nb, 1024, 0, stream>>>(rp, cur, bsum, N, E);
  scatter_k<<<2048, 256, 0, stream>>>(esrc, edst, ew, cur, edge, E, N);

  int gblocks = (N + 63) / 64;
  ingemm_k<<<gblocks, 256, 0, stream>>>(x, Win, bin, x0, N);

  const unsigned short* hin = x0;
  unsigned short* bufs[2] = {ha, hb};
  for (int l = 0; l < NC; ++l) {
    float beta = logf(0.5f / (float)(l + 1) + 1.0f);
    unsigned short* ho = bufs[l & 1];
    spmm_k<<<2048, 256, 0, stream>>>((const ushort4*)hin, (const ushort4*)x0, rp, edge, (ushort4*)hhb, N);
    gemm_k<<<gblocks, 256, 0, stream>>>(hhb, convW + (size_t)l * 64 * 64, ho, beta, N);
    hin = ho;
  }
  out_k<<<gblocks, 256, 0, stream>>>(hin, Wout, bout, out, N);
}